// Round 5
// baseline (1054.627 us; speedup 1.0000x reference)
//
#include <hip/hip_runtime.h>
#include <hip/hip_bf16.h>

// GCN: 3x GCNConv (512->128->64->32) + global max pool + FC(32->10) + log_softmax
// N=100000 nodes, E=1600000 edges, 64 graphs.
//
// Round 5:
//  - XCD-pinned partitioned fill_adj (kills cross-XCD write ping-pong: 105MB->~10MB HBM writes)
//  - bf16 hs (GEMM outputs bf16; gathers read bf16) -> halves gather/GEMM-write traffic
//  - dinv fused into scan1

typedef __attribute__((ext_vector_type(8))) short short8;
typedef __attribute__((ext_vector_type(8))) unsigned short ushort8v;
typedef __attribute__((ext_vector_type(4))) float f32x4;

__device__ __forceinline__ unsigned short f2bf(float f) {
    __hip_bfloat16 h = __float2bfloat16(f);
    return *(unsigned short*)&h;
}
__device__ __forceinline__ float bfu2f(unsigned short u) {
    unsigned int v = ((unsigned int)u) << 16;
    return __uint_as_float(v);
}

// ---------------- init: zero deg counters + pooled ----------------
__global__ void init_kernel(int* __restrict__ cnt, float* __restrict__ pooled, int N) {
    int i = blockIdx.x * 256 + threadIdx.x;
    if (i < N) cnt[i] = 0;
    if (i < 64 * 32) pooled[i] = 0.0f;  // post-relu values >= 0
}

__global__ void deg_count(const int* __restrict__ dst, int* __restrict__ cnt, int E) {
    int e = blockIdx.x * 256 + threadIdx.x;
    if (e < E) atomicAdd(&cnt[dst[e]], 1);
}

// ---------------- exclusive scan of cnt -> rowstart; dinv fused ----------------
__global__ void scan1(const int* __restrict__ cnt, int* __restrict__ rowstart,
                      int* __restrict__ bsums, float* __restrict__ dinv, int N) {
    __shared__ int s[256];
    int i = blockIdx.x * 256 + threadIdx.x;
    int v = (i < N) ? cnt[i] : 0;
    if (i < N) dinv[i] = rsqrtf(1.0f + (float)v);  // +1 self loop
    s[threadIdx.x] = v;
    __syncthreads();
    for (int off = 1; off < 256; off <<= 1) {
        int t = (threadIdx.x >= off) ? s[threadIdx.x - off] : 0;
        __syncthreads();
        s[threadIdx.x] += t;
        __syncthreads();
    }
    if (i < N) rowstart[i] = s[threadIdx.x] - v;  // exclusive
    if (threadIdx.x == 255) bsums[blockIdx.x] = s[255];
}

__global__ void scan2(int* __restrict__ bsums, int nb) {
    __shared__ int s[512];
    int t = threadIdx.x;
    int v = (t < nb) ? bsums[t] : 0;
    s[t] = v;
    __syncthreads();
    for (int off = 1; off < 512; off <<= 1) {
        int u = (t >= off) ? s[t - off] : 0;
        __syncthreads();
        s[t] += u;
        __syncthreads();
    }
    if (t < nb) bsums[t] = s[t] - v;  // exclusive
}

__global__ void scan3(int* __restrict__ rowstart, const int* __restrict__ bsums,
                      int* __restrict__ cursor, int N, int E) {
    int i = blockIdx.x * 256 + threadIdx.x;
    if (i < N) {
        int r = rowstart[i] + bsums[blockIdx.x];
        rowstart[i] = r;
        cursor[i] = r;
    }
    if (i == 0) rowstart[N] = E;
}

// ---------------- partitioned fill_adj: 8 chunks x 64 partitions ----------------
// blockIdx = c*64 + p -> all chunks of partition p on XCD p%8 (blockIdx%8 round-robin).
// Each adj region [rowstart of partition p] is written by exactly one XCD.
__global__ void fill_adj_part(const int* __restrict__ src, const int* __restrict__ dst,
                              int* __restrict__ cursor, int* __restrict__ adj,
                              int E, int npp) {
    const int p = blockIdx.x & 63;
    const int c = blockIdx.x >> 6;
    const int lo = p * npp, hi = lo + npp;
    const int e0 = (int)((long)c * E / 8);
    const int e1 = (int)((long)(c + 1) * E / 8);
    for (int e = e0 + threadIdx.x; e < e1; e += 256) {
        int d = dst[e];
        if (d >= lo && d < hi) {
            int pos = atomicAdd(&cursor[d], 1);
            adj[pos] = src[e];
        }
    }
}

// ---------------- W[K][N] f32 -> Wt[N][K] bf16 ----------------
__global__ void wconv(const float* __restrict__ W, unsigned short* __restrict__ Wt,
                      int K, int N) {
    int idx = blockIdx.x * 256 + threadIdx.x;
    if (idx < N * K) {
        int n = idx / K, k = idx % K;
        Wt[idx] = f2bf(W[(size_t)k * N + n]);
    }
}

// ---------------- MFMA GEMM: C_bf16[M x NOUT] = dinv .* (A[M x K] @ Wt^T) ----------------
template <int NOUT, bool A_BF16>
__global__ __launch_bounds__(256) void mfma_gemm(
        const float* __restrict__ Af, const unsigned short* __restrict__ Ab,
        const unsigned short* __restrict__ Wt, const float* __restrict__ dinv,
        unsigned short* __restrict__ C, int M, int K) {
    constexpr int NT = NOUT / 16;            // col tiles per wave: 8/4/2
    constexpr int CH = 136;                  // shorts per chunk (16*8 + 8 pad)

    __shared__ short As[16 * CH];            // 16 chunks (4 rowgroups x 4 kquads)
    __shared__ short Bs[NT * 4 * CH];        // NT*4 chunks

    const int t = threadIdx.x;
    const int w = t >> 6;                    // wave 0..3
    const int lane = t & 63;
    const int row0 = blockIdx.x * 64;

    f32x4 acc[NT];
#pragma unroll
    for (int c = 0; c < NT; ++c) acc[c] = (f32x4){0.f, 0.f, 0.f, 0.f};

    const int ar = t >> 2;                   // A row 0..63
    const int aq = t & 3;                    // A k-quad
    const int arow = row0 + ar;
    const int a_lds = ((ar >> 4) * 4 + aq) * CH + (ar & 15) * 8;

    const int bn = t >> 1;                   // Wt row (col of W)
    const int bh = t & 1;                    // k-half
    const int b_lds0 = ((bn >> 4) * 4 + 2 * bh) * CH + (bn & 15) * 8;

    for (int k0 = 0; k0 < K; k0 += 32) {
        short8 apack;
        if (A_BF16) {
            if (arow < M) apack = *(const short8*)&Ab[(size_t)arow * K + k0 + aq * 8];
            else apack = (short8){0, 0, 0, 0, 0, 0, 0, 0};
        } else {
            float4 u0 = make_float4(0.f, 0.f, 0.f, 0.f), u1 = u0;
            if (arow < M) {
                const float* ap = Af + (size_t)arow * K + k0 + aq * 8;
                u0 = *(const float4*)ap;
                u1 = *(const float4*)(ap + 4);
            }
            apack[0] = (short)f2bf(u0.x); apack[1] = (short)f2bf(u0.y);
            apack[2] = (short)f2bf(u0.z); apack[3] = (short)f2bf(u0.w);
            apack[4] = (short)f2bf(u1.x); apack[5] = (short)f2bf(u1.y);
            apack[6] = (short)f2bf(u1.z); apack[7] = (short)f2bf(u1.w);
        }
        short8 w0, w1;
        if (t < 2 * NOUT) {
            const unsigned short* wp = Wt + (size_t)bn * K + k0 + 16 * bh;
            w0 = *(const short8*)wp;
            w1 = *(const short8*)(wp + 8);
        }
        __syncthreads();
        *(short8*)&As[a_lds] = apack;
        if (t < 2 * NOUT) {
            *(short8*)&Bs[b_lds0] = w0;
            *(short8*)&Bs[b_lds0 + CH] = w1;
        }
        __syncthreads();

        short8 a = *(short8*)&As[(w * 4 + (lane >> 4)) * CH + (lane & 15) * 8];
#pragma unroll
        for (int c = 0; c < NT; ++c) {
            short8 b = *(short8*)&Bs[(c * 4 + (lane >> 4)) * CH + (lane & 15) * 8];
            acc[c] = __builtin_amdgcn_mfma_f32_16x16x32_bf16(a, b, acc[c], 0, 0, 0);
        }
    }

    const int q = lane >> 4, i = lane & 15;
#pragma unroll
    for (int reg = 0; reg < 4; ++reg) {
        int row = row0 + w * 16 + q * 4 + reg;
        if (row < M) {
            float di = dinv[row];
#pragma unroll
            for (int c = 0; c < NT; ++c)
                C[(size_t)row * NOUT + c * 16 + i] = f2bf(di * acc[c][reg]);
        }
    }
}

// ---------------- gather (bf16 hs): out = relu(dinv.*(hs[i]+sum_in hs[src])+b) ----------------
template <int F, bool OUT_BF16>
__global__ void gather_relu(const int* __restrict__ rowstart, const int* __restrict__ adj,
                            const float* __restrict__ dinv,
                            const unsigned short* __restrict__ hs,
                            const float* __restrict__ bias, void* __restrict__ outv, int N) {
    constexpr int F8 = F / 8;          // lanes per node (16/8/4)
    constexpr int NPB = 256 / F8;
    const int node = blockIdx.x * NPB + threadIdx.x / F8;
    if (node >= N) return;
    const int lane = threadIdx.x % F8;
    const size_t fo = (size_t)lane * 8;

    float acc[8];
    {
        ushort8v s = *(const ushort8v*)&hs[(size_t)node * F + fo];
#pragma unroll
        for (int i = 0; i < 8; ++i) acc[i] = bfu2f(s[i]);
    }
    int j = rowstart[node];
    const int end = rowstart[node + 1];

    for (; j + 4 <= end; j += 4) {
        int s0 = adj[j], s1 = adj[j + 1], s2 = adj[j + 2], s3 = adj[j + 3];
        ushort8v v0 = *(const ushort8v*)&hs[(size_t)s0 * F + fo];
        ushort8v v1 = *(const ushort8v*)&hs[(size_t)s1 * F + fo];
        ushort8v v2 = *(const ushort8v*)&hs[(size_t)s2 * F + fo];
        ushort8v v3 = *(const ushort8v*)&hs[(size_t)s3 * F + fo];
#pragma unroll
        for (int i = 0; i < 8; ++i)
            acc[i] += (bfu2f(v0[i]) + bfu2f(v1[i])) + (bfu2f(v2[i]) + bfu2f(v3[i]));
    }
    for (; j < end; ++j) {
        int s = adj[j];
        ushort8v v = *(const ushort8v*)&hs[(size_t)s * F + fo];
#pragma unroll
        for (int i = 0; i < 8; ++i) acc[i] += bfu2f(v[i]);
    }

    const float di = dinv[node];
    if (OUT_BF16) {
        ushort8v o;
#pragma unroll
        for (int i = 0; i < 8; ++i) o[i] = f2bf(fmaxf(di * acc[i] + bias[fo + i], 0.f));
        *(ushort8v*)&((unsigned short*)outv)[(size_t)node * F + fo] = o;
    } else {
        float ov[8];
#pragma unroll
        for (int i = 0; i < 8; ++i) ov[i] = fmaxf(di * acc[i] + bias[fo + i], 0.f);
        float4* op = (float4*)&((float*)outv)[(size_t)node * F + fo];
        op[0] = make_float4(ov[0], ov[1], ov[2], ov[3]);
        op[1] = make_float4(ov[4], ov[5], ov[6], ov[7]);
    }
}

// ---------------- segment max pool (batch sorted, values >= 0) ----------------
__global__ void pool_max(const float* __restrict__ h, const int* __restrict__ batch,
                         float* __restrict__ pooled, int N) {
    int t = blockIdx.x * 256 + threadIdx.x;
    int f = t % 32;
    int i0 = (t / 32) * 32;
    if (i0 >= N) return;
    int gcur = -1;
    float vmax = 0.f;
    for (int j = 0; j < 32; ++j) {
        int i = i0 + j;
        if (i >= N) break;
        int g = batch[i];
        if (g != gcur) {
            if (gcur >= 0) atomicMax((int*)&pooled[gcur * 32 + f], __float_as_int(vmax));
            gcur = g;
            vmax = 0.f;
        }
        vmax = fmaxf(vmax, h[(size_t)i * 32 + f]);
    }
    if (gcur >= 0) atomicMax((int*)&pooled[gcur * 32 + f], __float_as_int(vmax));
}

// ---------------- head ----------------
__global__ void head_kernel(const float* __restrict__ pooled, const float* __restrict__ Wfc,
                            const float* __restrict__ bfc, float* __restrict__ out) {
    int g = threadIdx.x;  // 64 graphs
    float p[32];
#pragma unroll
    for (int f = 0; f < 32; ++f) p[f] = pooled[g * 32 + f];
    float logits[10];
#pragma unroll
    for (int c = 0; c < 10; ++c) {
        float acc = bfc[c];
#pragma unroll
        for (int f = 0; f < 32; ++f) acc += p[f] * Wfc[f * 10 + c];
        logits[c] = acc;
    }
    float m = logits[0];
#pragma unroll
    for (int c = 1; c < 10; ++c) m = fmaxf(m, logits[c]);
    float s = 0.f;
#pragma unroll
    for (int c = 0; c < 10; ++c) s += expf(logits[c] - m);
    float lse = m + logf(s);
#pragma unroll
    for (int c = 0; c < 10; ++c) out[g * 10 + c] = logits[c] - lse;
}

extern "C" void kernel_launch(void* const* d_in, const int* in_sizes, int n_in,
                              void* d_out, int out_size, void* d_ws, size_t ws_size,
                              hipStream_t stream) {
    const float* x   = (const float*)d_in[0];
    const int*   ei  = (const int*)d_in[1];
    const int*   bat = (const int*)d_in[2];
    const float* W1  = (const float*)d_in[3];
    const float* b1  = (const float*)d_in[4];
    const float* W2  = (const float*)d_in[5];
    const float* b2  = (const float*)d_in[6];
    const float* W3  = (const float*)d_in[7];
    const float* b3  = (const float*)d_in[8];
    const float* Wfc = (const float*)d_in[9];
    const float* bfc = (const float*)d_in[10];
    float* out = (float*)d_out;

    const int N = in_sizes[2];        // 100000
    const int E = in_sizes[1] / 2;    // 1600000
    const int K0 = in_sizes[0] / N;   // 512

    const int* src = ei;
    const int* dst = ei + E;

    float* ws = (float*)d_ws;
    float* dinv = ws;                                        // N f32
    unsigned short* HS  = (unsigned short*)(ws + N);         // N*128 bf16 (GEMM out)
    unsigned short* ACT = HS + (size_t)N * 128;              // N*128 bf16 (activations)
    float* H3 = (float*)ACT;                                 // N*32 f32 (aliases ACT, used after GEMM3)
    float* pooled = (float*)(ACT + (size_t)N * 128);         // 2048 f32
    unsigned short* Wt1 = (unsigned short*)(pooled + 2048);  // 128*512 bf16
    unsigned short* Wt2 = Wt1 + 128 * 512;                   // 64*128
    unsigned short* Wt3 = Wt2 + 64 * 128;                    // 32*64
    int* iws = (int*)(Wt3 + 32 * 64);
    int* rowstart = iws;                           // N+1
    int* cursor = rowstart + (N + 1);              // N
    int* bsums = cursor + N;                       // 1024
    int* adj = bsums + 1024;                       // E

    const int nb = (N + 255) / 256;
    const int eb = (E + 255) / 256;
    const int gb = (N + 63) / 64;
    const int npp = (N + 63) / 64;                 // nodes per partition (1563)

    // ---- CSR build + dinv ----
    init_kernel<<<nb, 256, 0, stream>>>(cursor, pooled, N);
    deg_count<<<eb, 256, 0, stream>>>(dst, cursor, E);
    scan1<<<nb, 256, 0, stream>>>(cursor, rowstart, bsums, dinv, N);
    scan2<<<1, 512, 0, stream>>>(bsums, nb);
    scan3<<<nb, 256, 0, stream>>>(rowstart, bsums, cursor, N, E);
    fill_adj_part<<<512, 256, 0, stream>>>(src, dst, cursor, adj, E, npp);

    // ---- weight transpose+convert ----
    wconv<<<(128 * 512 + 255) / 256, 256, 0, stream>>>(W1, Wt1, K0, 128);
    wconv<<<(64 * 128 + 255) / 256, 256, 0, stream>>>(W2, Wt2, 128, 64);
    wconv<<<(32 * 64 + 255) / 256, 256, 0, stream>>>(W3, Wt3, 64, 32);

    const int gath128 = (N + 15) / 16;   // F=128: 16 nodes/block
    const int gath64  = (N + 31) / 32;   // F=64:  32 nodes/block
    const int gath32  = (N + 63) / 64;   // F=32:  64 nodes/block

    // ---- layer 1: 512 -> 128 (A = x f32) ----
    mfma_gemm<128, false><<<gb, 256, 0, stream>>>(x, nullptr, Wt1, dinv, HS, N, K0);
    gather_relu<128, true><<<gath128, 256, 0, stream>>>(rowstart, adj, dinv, HS, b1, ACT, N);

    // ---- layer 2: 128 -> 64 ----
    mfma_gemm<64, true><<<gb, 256, 0, stream>>>(nullptr, ACT, Wt2, dinv, HS, N, 128);
    gather_relu<64, true><<<gath64, 256, 0, stream>>>(rowstart, adj, dinv, HS, b2, ACT, N);

    // ---- layer 3: 64 -> 32 ----
    mfma_gemm<32, true><<<gb, 256, 0, stream>>>(nullptr, ACT, Wt3, dinv, HS, N, 64);
    gather_relu<32, false><<<gath32, 256, 0, stream>>>(rowstart, adj, dinv, HS, b3, H3, N);

    // ---- pool + head ----
    pool_max<<<(((N + 31) / 32) * 32 + 255) / 256, 256, 0, stream>>>(H3, bat, pooled, N);
    head_kernel<<<1, 64, 0, stream>>>(pooled, Wfc, bfc, out);
}

// Round 6
// 609.691 us; speedup vs baseline: 1.7298x; 1.7298x over previous
//
#include <hip/hip_runtime.h>
#include <hip/hip_bf16.h>

// GCN: 3x GCNConv (512->128->64->32) + global max pool + FC(32->10) + log_softmax
// N=100000 nodes, E=1600000 edges, 64 graphs.
//
// Round 6:
//  - One-pass slab CSR build: cnt[d]++ returns slot, slab[d*64+slot]=src.
//    Removes deg_count + 3-phase scan (counting and filling share one atomic).
//    Capacity 64 per node: deg ~ Poisson(16), P(>=64) ~ 2e-18/node.
//  - Keep round-5 bf16 GEMMs (MFMA 16x16x32) + bf16 gathers.

typedef __attribute__((ext_vector_type(8))) short short8;
typedef __attribute__((ext_vector_type(8))) unsigned short ushort8v;
typedef __attribute__((ext_vector_type(4))) float f32x4;

__device__ __forceinline__ unsigned short f2bf(float f) {
    __hip_bfloat16 h = __float2bfloat16(f);
    return *(unsigned short*)&h;
}
__device__ __forceinline__ float bfu2f(unsigned short u) {
    unsigned int v = ((unsigned int)u) << 16;
    return __uint_as_float(v);
}

// ---------------- init: zero slab counters + pooled ----------------
__global__ void init_kernel(int* __restrict__ cnt, float* __restrict__ pooled, int N) {
    int i = blockIdx.x * 256 + threadIdx.x;
    if (i < N) cnt[i] = 0;
    if (i < 64 * 32) pooled[i] = 0.0f;  // post-relu values >= 0
}

// ---------------- one-pass slab fill: cnt[d]++ gives slot ----------------
__global__ void fill_slab(const int* __restrict__ src, const int* __restrict__ dst,
                          int* __restrict__ cnt, int* __restrict__ slab, int E) {
    int e = blockIdx.x * 256 + threadIdx.x;
    if (e < E) {
        int d = dst[e];
        int pos = atomicAdd(&cnt[d], 1);
        if (pos < 64) slab[(size_t)d * 64 + pos] = src[e];
    }
}

__global__ void dinv_kernel(const int* __restrict__ cnt, float* __restrict__ dinv, int N) {
    int i = blockIdx.x * 256 + threadIdx.x;
    if (i < N) dinv[i] = rsqrtf(1.0f + (float)cnt[i]);  // +1 self loop
}

// ---------------- W[K][N] f32 -> Wt[N][K] bf16 ----------------
__global__ void wconv(const float* __restrict__ W, unsigned short* __restrict__ Wt,
                      int K, int N) {
    int idx = blockIdx.x * 256 + threadIdx.x;
    if (idx < N * K) {
        int n = idx / K, k = idx % K;
        Wt[idx] = f2bf(W[(size_t)k * N + n]);
    }
}

// ---------------- MFMA GEMM: C_bf16[M x NOUT] = dinv .* (A[M x K] @ Wt^T) ----------------
template <int NOUT, bool A_BF16>
__global__ __launch_bounds__(256) void mfma_gemm(
        const float* __restrict__ Af, const unsigned short* __restrict__ Ab,
        const unsigned short* __restrict__ Wt, const float* __restrict__ dinv,
        unsigned short* __restrict__ C, int M, int K) {
    constexpr int NT = NOUT / 16;            // col tiles per wave: 8/4/2
    constexpr int CH = 136;                  // shorts per chunk (16*8 + 8 pad)

    __shared__ short As[16 * CH];            // 16 chunks (4 rowgroups x 4 kquads)
    __shared__ short Bs[NT * 4 * CH];        // NT*4 chunks

    const int t = threadIdx.x;
    const int w = t >> 6;                    // wave 0..3
    const int lane = t & 63;
    const int row0 = blockIdx.x * 64;

    f32x4 acc[NT];
#pragma unroll
    for (int c = 0; c < NT; ++c) acc[c] = (f32x4){0.f, 0.f, 0.f, 0.f};

    const int ar = t >> 2;                   // A row 0..63
    const int aq = t & 3;                    // A k-quad
    const int arow = row0 + ar;
    const int a_lds = ((ar >> 4) * 4 + aq) * CH + (ar & 15) * 8;

    const int bn = t >> 1;                   // Wt row (col of W)
    const int bh = t & 1;                    // k-half
    const int b_lds0 = ((bn >> 4) * 4 + 2 * bh) * CH + (bn & 15) * 8;

    for (int k0 = 0; k0 < K; k0 += 32) {
        short8 apack;
        if (A_BF16) {
            if (arow < M) apack = *(const short8*)&Ab[(size_t)arow * K + k0 + aq * 8];
            else apack = (short8){0, 0, 0, 0, 0, 0, 0, 0};
        } else {
            float4 u0 = make_float4(0.f, 0.f, 0.f, 0.f), u1 = u0;
            if (arow < M) {
                const float* ap = Af + (size_t)arow * K + k0 + aq * 8;
                u0 = *(const float4*)ap;
                u1 = *(const float4*)(ap + 4);
            }
            apack[0] = (short)f2bf(u0.x); apack[1] = (short)f2bf(u0.y);
            apack[2] = (short)f2bf(u0.z); apack[3] = (short)f2bf(u0.w);
            apack[4] = (short)f2bf(u1.x); apack[5] = (short)f2bf(u1.y);
            apack[6] = (short)f2bf(u1.z); apack[7] = (short)f2bf(u1.w);
        }
        short8 w0, w1;
        if (t < 2 * NOUT) {
            const unsigned short* wp = Wt + (size_t)bn * K + k0 + 16 * bh;
            w0 = *(const short8*)wp;
            w1 = *(const short8*)(wp + 8);
        }
        __syncthreads();
        *(short8*)&As[a_lds] = apack;
        if (t < 2 * NOUT) {
            *(short8*)&Bs[b_lds0] = w0;
            *(short8*)&Bs[b_lds0 + CH] = w1;
        }
        __syncthreads();

        short8 a = *(short8*)&As[(w * 4 + (lane >> 4)) * CH + (lane & 15) * 8];
#pragma unroll
        for (int c = 0; c < NT; ++c) {
            short8 b = *(short8*)&Bs[(c * 4 + (lane >> 4)) * CH + (lane & 15) * 8];
            acc[c] = __builtin_amdgcn_mfma_f32_16x16x32_bf16(a, b, acc[c], 0, 0, 0);
        }
    }

    const int q = lane >> 4, i = lane & 15;
#pragma unroll
    for (int reg = 0; reg < 4; ++reg) {
        int row = row0 + w * 16 + q * 4 + reg;
        if (row < M) {
            float di = dinv[row];
#pragma unroll
            for (int c = 0; c < NT; ++c)
                C[(size_t)row * NOUT + c * 16 + i] = f2bf(di * acc[c][reg]);
        }
    }
}

// ---------------- gather (bf16 hs, slab adjacency) ----------------
// out = relu(dinv .* (hs[i] + sum_in hs[src]) + b)
template <int F, bool OUT_BF16>
__global__ void gather_relu(const int* __restrict__ cnt, const int* __restrict__ slab,
                            const float* __restrict__ dinv,
                            const unsigned short* __restrict__ hs,
                            const float* __restrict__ bias, void* __restrict__ outv, int N) {
    constexpr int F8 = F / 8;          // lanes per node (16/8/4)
    constexpr int NPB = 256 / F8;
    const int node = blockIdx.x * NPB + threadIdx.x / F8;
    if (node >= N) return;
    const int lane = threadIdx.x % F8;
    const size_t fo = (size_t)lane * 8;

    float acc[8];
    {
        ushort8v s = *(const ushort8v*)&hs[(size_t)node * F + fo];
#pragma unroll
        for (int i = 0; i < 8; ++i) acc[i] = bfu2f(s[i]);
    }
    const int deg = cnt[node];
    const int* sl = slab + (size_t)node * 64;

    int j = 0;
    for (; j + 4 <= deg; j += 4) {
        int4 s4 = *(const int4*)&sl[j];
        ushort8v v0 = *(const ushort8v*)&hs[(size_t)s4.x * F + fo];
        ushort8v v1 = *(const ushort8v*)&hs[(size_t)s4.y * F + fo];
        ushort8v v2 = *(const ushort8v*)&hs[(size_t)s4.z * F + fo];
        ushort8v v3 = *(const ushort8v*)&hs[(size_t)s4.w * F + fo];
#pragma unroll
        for (int i = 0; i < 8; ++i)
            acc[i] += (bfu2f(v0[i]) + bfu2f(v1[i])) + (bfu2f(v2[i]) + bfu2f(v3[i]));
    }
    for (; j < deg; ++j) {
        int s = sl[j];
        ushort8v v = *(const ushort8v*)&hs[(size_t)s * F + fo];
#pragma unroll
        for (int i = 0; i < 8; ++i) acc[i] += bfu2f(v[i]);
    }

    const float di = dinv[node];
    if (OUT_BF16) {
        ushort8v o;
#pragma unroll
        for (int i = 0; i < 8; ++i) o[i] = f2bf(fmaxf(di * acc[i] + bias[fo + i], 0.f));
        *(ushort8v*)&((unsigned short*)outv)[(size_t)node * F + fo] = o;
    } else {
        float ov[8];
#pragma unroll
        for (int i = 0; i < 8; ++i) ov[i] = fmaxf(di * acc[i] + bias[fo + i], 0.f);
        float4* op = (float4*)&((float*)outv)[(size_t)node * F + fo];
        op[0] = make_float4(ov[0], ov[1], ov[2], ov[3]);
        op[1] = make_float4(ov[4], ov[5], ov[6], ov[7]);
    }
}

// ---------------- segment max pool (batch sorted, values >= 0) ----------------
__global__ void pool_max(const float* __restrict__ h, const int* __restrict__ batch,
                         float* __restrict__ pooled, int N) {
    int t = blockIdx.x * 256 + threadIdx.x;
    int f = t % 32;
    int i0 = (t / 32) * 32;
    if (i0 >= N) return;
    int gcur = -1;
    float vmax = 0.f;
    for (int j = 0; j < 32; ++j) {
        int i = i0 + j;
        if (i >= N) break;
        int g = batch[i];
        if (g != gcur) {
            if (gcur >= 0) atomicMax((int*)&pooled[gcur * 32 + f], __float_as_int(vmax));
            gcur = g;
            vmax = 0.f;
        }
        vmax = fmaxf(vmax, h[(size_t)i * 32 + f]);
    }
    if (gcur >= 0) atomicMax((int*)&pooled[gcur * 32 + f], __float_as_int(vmax));
}

// ---------------- head ----------------
__global__ void head_kernel(const float* __restrict__ pooled, const float* __restrict__ Wfc,
                            const float* __restrict__ bfc, float* __restrict__ out) {
    int g = threadIdx.x;  // 64 graphs
    float p[32];
#pragma unroll
    for (int f = 0; f < 32; ++f) p[f] = pooled[g * 32 + f];
    float logits[10];
#pragma unroll
    for (int c = 0; c < 10; ++c) {
        float acc = bfc[c];
#pragma unroll
        for (int f = 0; f < 32; ++f) acc += p[f] * Wfc[f * 10 + c];
        logits[c] = acc;
    }
    float m = logits[0];
#pragma unroll
    for (int c = 1; c < 10; ++c) m = fmaxf(m, logits[c]);
    float s = 0.f;
#pragma unroll
    for (int c = 0; c < 10; ++c) s += expf(logits[c] - m);
    float lse = m + logf(s);
#pragma unroll
    for (int c = 0; c < 10; ++c) out[g * 10 + c] = logits[c] - lse;
}

extern "C" void kernel_launch(void* const* d_in, const int* in_sizes, int n_in,
                              void* d_out, int out_size, void* d_ws, size_t ws_size,
                              hipStream_t stream) {
    const float* x   = (const float*)d_in[0];
    const int*   ei  = (const int*)d_in[1];
    const int*   bat = (const int*)d_in[2];
    const float* W1  = (const float*)d_in[3];
    const float* b1  = (const float*)d_in[4];
    const float* W2  = (const float*)d_in[5];
    const float* b2  = (const float*)d_in[6];
    const float* W3  = (const float*)d_in[7];
    const float* b3  = (const float*)d_in[8];
    const float* Wfc = (const float*)d_in[9];
    const float* bfc = (const float*)d_in[10];
    float* out = (float*)d_out;

    const int N = in_sizes[2];        // 100000
    const int E = in_sizes[1] / 2;    // 1600000
    const int K0 = in_sizes[0] / N;   // 512

    const int* src = ei;
    const int* dst = ei + E;

    float* ws = (float*)d_ws;
    float* dinv = ws;                                        // N f32
    unsigned short* HS  = (unsigned short*)(ws + N);         // N*128 bf16 (GEMM out)
    unsigned short* ACT = HS + (size_t)N * 128;              // N*128 bf16 (activations)
    float* H3 = (float*)ACT;                                 // N*32 f32 (aliases ACT, used after GEMM3)
    float* pooled = (float*)(ACT + (size_t)N * 128);         // 2048 f32
    unsigned short* Wt1 = (unsigned short*)(pooled + 2048);  // 128*512 bf16
    unsigned short* Wt2 = Wt1 + 128 * 512;                   // 64*128
    unsigned short* Wt3 = Wt2 + 64 * 128;                    // 32*64
    int* iws = (int*)(Wt3 + 32 * 64);
    int* cnt = iws;                                // N
    int* slab = cnt + N;                           // N*64

    const int nb = (N + 255) / 256;
    const int eb = (E + 255) / 256;
    const int gb = (N + 63) / 64;

    // ---- slab CSR build + dinv ----
    init_kernel<<<nb, 256, 0, stream>>>(cnt, pooled, N);
    fill_slab<<<eb, 256, 0, stream>>>(src, dst, cnt, slab, E);
    dinv_kernel<<<nb, 256, 0, stream>>>(cnt, dinv, N);

    // ---- weight transpose+convert ----
    wconv<<<(128 * 512 + 255) / 256, 256, 0, stream>>>(W1, Wt1, K0, 128);
    wconv<<<(64 * 128 + 255) / 256, 256, 0, stream>>>(W2, Wt2, 128, 64);
    wconv<<<(32 * 64 + 255) / 256, 256, 0, stream>>>(W3, Wt3, 64, 32);

    const int gath128 = (N + 15) / 16;   // F=128: 16 nodes/block
    const int gath64  = (N + 31) / 32;   // F=64:  32 nodes/block
    const int gath32  = (N + 63) / 64;   // F=32:  64 nodes/block

    // ---- layer 1: 512 -> 128 (A = x f32) ----
    mfma_gemm<128, false><<<gb, 256, 0, stream>>>(x, nullptr, Wt1, dinv, HS, N, K0);
    gather_relu<128, true><<<gath128, 256, 0, stream>>>(cnt, slab, dinv, HS, b1, ACT, N);

    // ---- layer 2: 128 -> 64 ----
    mfma_gemm<64, true><<<gb, 256, 0, stream>>>(nullptr, ACT, Wt2, dinv, HS, N, 128);
    gather_relu<64, true><<<gath64, 256, 0, stream>>>(cnt, slab, dinv, HS, b2, ACT, N);

    // ---- layer 3: 64 -> 32 ----
    mfma_gemm<32, true><<<gb, 256, 0, stream>>>(nullptr, ACT, Wt3, dinv, HS, N, 64);
    gather_relu<32, false><<<gath32, 256, 0, stream>>>(cnt, slab, dinv, HS, b3, H3, N);

    // ---- pool + head ----
    pool_max<<<(((N + 31) / 32) * 32 + 255) / 256, 256, 0, stream>>>(H3, bat, pooled, N);
    head_kernel<<<1, 64, 0, stream>>>(pooled, Wfc, bfc, out);
}